// Round 1
// baseline (687.648 us; speedup 1.0000x reference)
//
#include <hip/hip_runtime.h>
#include <hip/hip_bf16.h>

// GCN on MI355X. Strategy: build CSR-by-dst on device (histogram+scan+fill,
// int atomics only), then pull-style aggregation (no float atomics, fused
// self-loop+bias+relu). h matrices (6.4MB) are L2-resident -> gathers hit cache.
// Workspace: ~27.2 MB.

#define NNODES 100000
#define NEDGES 3200000

__global__ __launch_bounds__(256) void hist_k(const int* __restrict__ dst,
                                              int* __restrict__ deg) {
    int e = blockIdx.x * 256 + threadIdx.x;
    if (e < NEDGES) atomicAdd(&deg[dst[e]], 1);
}

__global__ __launch_bounds__(256) void dinv_k(const int* __restrict__ deg,
                                              float* __restrict__ dinv) {
    int i = blockIdx.x * 256 + threadIdx.x;
    if (i < NNODES) dinv[i] = rsqrtf((float)deg[i] + 1.0f);
}

// Per-block exclusive scan of deg -> rs, block totals -> bsum.
__global__ __launch_bounds__(256) void scan1_k(const int* __restrict__ deg,
                                               int* __restrict__ rs,
                                               int* __restrict__ bsum) {
    __shared__ int s[256];
    int t = threadIdx.x;
    int i = blockIdx.x * 256 + t;
    int v = (i < NNODES) ? deg[i] : 0;
    s[t] = v;
    __syncthreads();
#pragma unroll
    for (int off = 1; off < 256; off <<= 1) {
        int x = (t >= off) ? s[t - off] : 0;
        __syncthreads();
        s[t] += x;
        __syncthreads();
    }
    if (i < NNODES) rs[i] = s[t] - v;  // exclusive within block
    if (t == 255) bsum[blockIdx.x] = s[255];
}

// Single-block exclusive scan of block sums (nb <= 512).
__global__ __launch_bounds__(512) void scan2_k(int* __restrict__ bsum, int nb) {
    __shared__ int s[512];
    int t = threadIdx.x;
    int v = (t < nb) ? bsum[t] : 0;
    s[t] = v;
    __syncthreads();
    for (int off = 1; off < 512; off <<= 1) {
        int x = (t >= off) ? s[t - off] : 0;
        __syncthreads();
        s[t] += x;
        __syncthreads();
    }
    if (t < nb) bsum[t] = s[t] - v;  // exclusive
}

// Add block offsets; also produce the fill cursor copy.
__global__ __launch_bounds__(256) void scan3_k(int* __restrict__ rs,
                                               int* __restrict__ cur,
                                               const int* __restrict__ bsum) {
    int i = blockIdx.x * 256 + threadIdx.x;
    if (i < NNODES) {
        int v = rs[i] + bsum[i >> 8];
        rs[i] = v;
        cur[i] = v;
    }
}

__global__ __launch_bounds__(256) void fill_k(const int* __restrict__ src,
                                              const int* __restrict__ dst,
                                              int* __restrict__ cur,
                                              int* __restrict__ csr) {
    int e = blockIdx.x * 256 + threadIdx.x;
    if (e < NEDGES) {
        int p = atomicAdd(&cur[dst[e]], 1);
        csr[p] = src[e];
    }
}

// buf0 = x @ W1   (x: [N,128], W1: [128,16])
__global__ __launch_bounds__(256) void gemm1_k(const float* __restrict__ x,
                                               const float* __restrict__ W,
                                               float* __restrict__ out) {
    __shared__ float w[2048];
    for (int j = threadIdx.x; j < 2048; j += 256) w[j] = W[j];
    __syncthreads();
    int i = blockIdx.x * 256 + threadIdx.x;
    if (i >= NNODES) return;
    float acc[16];
#pragma unroll
    for (int c = 0; c < 16; c++) acc[c] = 0.f;
    const float4* xr = (const float4*)(x + (size_t)i * 128);
#pragma unroll 8
    for (int k4 = 0; k4 < 32; k4++) {
        float4 xv = xr[k4];
        const float* wr = &w[k4 * 64];
#pragma unroll
        for (int c = 0; c < 16; c++)
            acc[c] = fmaf(xv.x, wr[c],
                     fmaf(xv.y, wr[16 + c],
                     fmaf(xv.z, wr[32 + c],
                     fmaf(xv.w, wr[48 + c], acc[c]))));
    }
    float4* op = (float4*)(out + (size_t)i * 16);
    op[0] = make_float4(acc[0], acc[1], acc[2], acc[3]);
    op[1] = make_float4(acc[4], acc[5], acc[6], acc[7]);
    op[2] = make_float4(acc[8], acc[9], acc[10], acc[11]);
    op[3] = make_float4(acc[12], acc[13], acc[14], acc[15]);
}

// out[i] = relu( dinv[i]*sum_{e:dst=i} dinv[s]*h[s] + dinv[i]^2*h[i] + b )
__global__ __launch_bounds__(256) void agg_k(const float* __restrict__ h,
                                             const int* __restrict__ csr,
                                             const int* __restrict__ rs,
                                             const int* __restrict__ deg,
                                             const float* __restrict__ dinv,
                                             const float* __restrict__ bias,
                                             float* __restrict__ out) {
    __shared__ float b[16];
    if (threadIdx.x < 16) b[threadIdx.x] = bias[threadIdx.x];
    __syncthreads();
    int i = blockIdx.x * 256 + threadIdx.x;
    if (i >= NNODES) return;
    int base = rs[i];
    int cnt = deg[i];
    float acc[16];
#pragma unroll
    for (int c = 0; c < 16; c++) acc[c] = 0.f;
#pragma unroll 2
    for (int j = 0; j < cnt; j++) {
        int s = csr[base + j];
        float w = dinv[s];
        const float4* hr = (const float4*)(h + (size_t)s * 16);
        float hv[16];
        *(float4*)&hv[0]  = hr[0];
        *(float4*)&hv[4]  = hr[1];
        *(float4*)&hv[8]  = hr[2];
        *(float4*)&hv[12] = hr[3];
#pragma unroll
        for (int c = 0; c < 16; c++) acc[c] = fmaf(w, hv[c], acc[c]);
    }
    float di = dinv[i];
    float d2 = di * di;
    const float4* hr = (const float4*)(h + (size_t)i * 16);
    float hv[16];
    *(float4*)&hv[0]  = hr[0];
    *(float4*)&hv[4]  = hr[1];
    *(float4*)&hv[8]  = hr[2];
    *(float4*)&hv[12] = hr[3];
    float o[16];
#pragma unroll
    for (int c = 0; c < 16; c++)
        o[c] = fmaxf(fmaf(di, acc[c], fmaf(d2, hv[c], b[c])), 0.f);
    float4* op = (float4*)(out + (size_t)i * 16);
    op[0] = *(float4*)&o[0];
    op[1] = *(float4*)&o[4];
    op[2] = *(float4*)&o[8];
    op[3] = *(float4*)&o[12];
}

// out = h @ W   (h: [N,16], W: [16,16])
__global__ __launch_bounds__(256) void gemm2_k(const float* __restrict__ h,
                                               const float* __restrict__ W,
                                               float* __restrict__ out) {
    __shared__ float w[256];
    w[threadIdx.x] = W[threadIdx.x];
    __syncthreads();
    int i = blockIdx.x * 256 + threadIdx.x;
    if (i >= NNODES) return;
    float hv[16];
    const float4* hr = (const float4*)(h + (size_t)i * 16);
    *(float4*)&hv[0]  = hr[0];
    *(float4*)&hv[4]  = hr[1];
    *(float4*)&hv[8]  = hr[2];
    *(float4*)&hv[12] = hr[3];
    float acc[16];
#pragma unroll
    for (int c = 0; c < 16; c++) acc[c] = 0.f;
#pragma unroll
    for (int k = 0; k < 16; k++) {
        float hk = hv[k];
#pragma unroll
        for (int c = 0; c < 16; c++) acc[c] = fmaf(hk, w[k * 16 + c], acc[c]);
    }
    float4* op = (float4*)(out + (size_t)i * 16);
    op[0] = make_float4(acc[0], acc[1], acc[2], acc[3]);
    op[1] = make_float4(acc[4], acc[5], acc[6], acc[7]);
    op[2] = make_float4(acc[8], acc[9], acc[10], acc[11]);
    op[3] = make_float4(acc[12], acc[13], acc[14], acc[15]);
}

// out[i] = relu(h @ l1w + l1b) @ l2w + l2b
__global__ __launch_bounds__(256) void mlp_k(const float* __restrict__ h,
                                             const float* __restrict__ l1w,
                                             const float* __restrict__ l1b,
                                             const float* __restrict__ l2w,
                                             const float* __restrict__ l2b,
                                             float* __restrict__ out) {
    __shared__ float w1[256];
    __shared__ float bb1[16];
    __shared__ float w2[16];
    __shared__ float bb2;
    int t = threadIdx.x;
    w1[t] = l1w[t];
    if (t < 16) bb1[t] = l1b[t];
    if (t >= 16 && t < 32) w2[t - 16] = l2w[t - 16];
    if (t == 32) bb2 = l2b[0];
    __syncthreads();
    int i = blockIdx.x * 256 + t;
    if (i >= NNODES) return;
    float hv[16];
    const float4* hr = (const float4*)(h + (size_t)i * 16);
    *(float4*)&hv[0]  = hr[0];
    *(float4*)&hv[4]  = hr[1];
    *(float4*)&hv[8]  = hr[2];
    *(float4*)&hv[12] = hr[3];
    float o = bb2;
#pragma unroll
    for (int j = 0; j < 16; j++) {
        float a = bb1[j];
#pragma unroll
        for (int k = 0; k < 16; k++) a = fmaf(hv[k], w1[k * 16 + j], a);
        o = fmaf(fmaxf(a, 0.f), w2[j], o);
    }
    out[i] = o;
}

extern "C" void kernel_launch(void* const* d_in, const int* in_sizes, int n_in,
                              void* d_out, int out_size, void* d_ws, size_t ws_size,
                              hipStream_t stream) {
    const float* x   = (const float*)d_in[0];
    const int*   ei  = (const int*)d_in[1];
    const float* W1  = (const float*)d_in[2];
    const float* b1  = (const float*)d_in[3];
    const float* W2  = (const float*)d_in[4];
    const float* b2  = (const float*)d_in[5];
    const float* l1w = (const float*)d_in[6];
    const float* l1b = (const float*)d_in[7];
    const float* l2w = (const float*)d_in[8];
    const float* l2b = (const float*)d_in[9];
    float* out = (float*)d_out;

    char* ws = (char*)d_ws;
    size_t off = 0;
    auto alloc = [&](size_t bytes) {
        size_t o = off;
        off += (bytes + 255) & ~(size_t)255;
        return o;
    };
    int*   deg  = (int*)(ws + alloc((size_t)NNODES * 4));
    int*   rs   = (int*)(ws + alloc((size_t)NNODES * 4));
    int*   cur  = (int*)(ws + alloc((size_t)NNODES * 4));
    int*   bsum = (int*)(ws + alloc(512 * 4));
    float* dinv = (float*)(ws + alloc((size_t)NNODES * 4));
    int*   csr  = (int*)(ws + alloc((size_t)NEDGES * 4));
    float* buf0 = (float*)(ws + alloc((size_t)NNODES * 16 * 4));
    float* buf1 = (float*)(ws + alloc((size_t)NNODES * 16 * 4));

    const int* srcv = ei;
    const int* dstv = ei + NEDGES;

    const int NB_N = (NNODES + 255) / 256;  // 391
    const int NB_E = (NEDGES + 255) / 256;  // 12500

    hipMemsetAsync(deg, 0, (size_t)NNODES * 4, stream);
    hist_k<<<NB_E, 256, 0, stream>>>(dstv, deg);
    dinv_k<<<NB_N, 256, 0, stream>>>(deg, dinv);
    scan1_k<<<NB_N, 256, 0, stream>>>(deg, rs, bsum);
    scan2_k<<<1, 512, 0, stream>>>(bsum, NB_N);
    scan3_k<<<NB_N, 256, 0, stream>>>(rs, cur, bsum);
    fill_k<<<NB_E, 256, 0, stream>>>(srcv, dstv, cur, csr);
    gemm1_k<<<NB_N, 256, 0, stream>>>(x, W1, buf0);
    agg_k<<<NB_N, 256, 0, stream>>>(buf0, csr, rs, deg, dinv, b1, buf1);
    gemm2_k<<<NB_N, 256, 0, stream>>>(buf1, W2, buf0);
    agg_k<<<NB_N, 256, 0, stream>>>(buf0, csr, rs, deg, dinv, b2, buf1);
    mlp_k<<<NB_N, 256, 0, stream>>>(buf1, l1w, l1b, l2w, l2b, out);
}

// Round 3
// 538.381 us; speedup vs baseline: 1.2773x; 1.2773x over previous
//
#include <hip/hip_runtime.h>
#include <hip/hip_bf16.h>

// GCN on MI355X. CSR-by-dst built on device, pull-style aggregation.
// R2: dst-range-partitioned fill (8 ranges ~ 8 XCDs) to kill cross-XCD
// cache-line false sharing on the csr scatter (R1: WRITE_SIZE 194MB, 290us).
// Fused gemm2 into agg1 epilogue, MLP into agg2 epilogue.
// R3: fix UB from R2 — float4 gathers must land in explicit float[16]
// arrays before scalar indexing (indexing 16 floats off &a0 read garbage).

#define NNODES 100000
#define NEDGES 3200000
#define NRANGE 8
#define RSPAN (NNODES / NRANGE)  // 12500

__global__ __launch_bounds__(256) void hist_k(const int* __restrict__ dst,
                                              int* __restrict__ deg) {
    int e = blockIdx.x * 256 + threadIdx.x;
    if (e < NEDGES) atomicAdd(&deg[dst[e]], 1);
}

__global__ __launch_bounds__(256) void dinv_k(const int* __restrict__ deg,
                                              float* __restrict__ dinv) {
    int i = blockIdx.x * 256 + threadIdx.x;
    if (i < NNODES) dinv[i] = rsqrtf((float)deg[i] + 1.0f);
}

// Per-block exclusive scan of deg -> rs, block totals -> bsum.
__global__ __launch_bounds__(256) void scan1_k(const int* __restrict__ deg,
                                               int* __restrict__ rs,
                                               int* __restrict__ bsum) {
    __shared__ int s[256];
    int t = threadIdx.x;
    int i = blockIdx.x * 256 + t;
    int v = (i < NNODES) ? deg[i] : 0;
    s[t] = v;
    __syncthreads();
#pragma unroll
    for (int off = 1; off < 256; off <<= 1) {
        int x = (t >= off) ? s[t - off] : 0;
        __syncthreads();
        s[t] += x;
        __syncthreads();
    }
    if (i < NNODES) rs[i] = s[t] - v;
    if (t == 255) bsum[blockIdx.x] = s[255];
}

__global__ __launch_bounds__(512) void scan2_k(int* __restrict__ bsum, int nb) {
    __shared__ int s[512];
    int t = threadIdx.x;
    int v = (t < nb) ? bsum[t] : 0;
    s[t] = v;
    __syncthreads();
    for (int off = 1; off < 512; off <<= 1) {
        int x = (t >= off) ? s[t - off] : 0;
        __syncthreads();
        s[t] += x;
        __syncthreads();
    }
    if (t < nb) bsum[t] = s[t] - v;
}

__global__ __launch_bounds__(256) void scan3_k(int* __restrict__ rs,
                                               int* __restrict__ cur,
                                               const int* __restrict__ bsum) {
    int i = blockIdx.x * 256 + threadIdx.x;
    if (i < NNODES) {
        int v = rs[i] + bsum[i >> 8];
        rs[i] = v;
        cur[i] = v;
    }
}

// Range-partitioned fill: block handles only dst in [r*RSPAN, (r+1)*RSPAN),
// r = blockIdx%8. With round-robin block->XCD dispatch, all writers of any
// csr cache line are on one XCD -> line dirtied in one L2, evicted once.
__global__ __launch_bounds__(256) void fillp_k(const int* __restrict__ src,
                                               const int* __restrict__ dst,
                                               int* __restrict__ cur,
                                               int* __restrict__ csr) {
    int r = blockIdx.x & (NRANGE - 1);
    int lo = r * RSPAN, hi = lo + RSPAN;
    const int4* s4 = (const int4*)src;
    const int4* d4 = (const int4*)dst;
    const int nq = NEDGES / 4;
    int stride = (gridDim.x >> 3) * 256;
    for (int q = (blockIdx.x >> 3) * 256 + threadIdx.x; q < nq; q += stride) {
        int4 d = d4[q];
        int4 s = s4[q];
        if (d.x >= lo && d.x < hi) { int p = atomicAdd(&cur[d.x], 1); csr[p] = s.x; }
        if (d.y >= lo && d.y < hi) { int p = atomicAdd(&cur[d.y], 1); csr[p] = s.y; }
        if (d.z >= lo && d.z < hi) { int p = atomicAdd(&cur[d.z], 1); csr[p] = s.z; }
        if (d.w >= lo && d.w < hi) { int p = atomicAdd(&cur[d.w], 1); csr[p] = s.w; }
    }
}

// buf0 = x @ W1   (x: [N,128], W1: [128,16])
__global__ __launch_bounds__(256) void gemm1_k(const float* __restrict__ x,
                                               const float* __restrict__ W,
                                               float* __restrict__ out) {
    __shared__ float w[2048];
    for (int j = threadIdx.x; j < 2048; j += 256) w[j] = W[j];
    __syncthreads();
    int i = blockIdx.x * 256 + threadIdx.x;
    if (i >= NNODES) return;
    float acc[16];
#pragma unroll
    for (int c = 0; c < 16; c++) acc[c] = 0.f;
    const float4* xr = (const float4*)(x + (size_t)i * 128);
#pragma unroll 8
    for (int k4 = 0; k4 < 32; k4++) {
        float4 xv = xr[k4];
        const float* wr = &w[k4 * 64];
#pragma unroll
        for (int c = 0; c < 16; c++)
            acc[c] = fmaf(xv.x, wr[c],
                     fmaf(xv.y, wr[16 + c],
                     fmaf(xv.z, wr[32 + c],
                     fmaf(xv.w, wr[48 + c], acc[c]))));
    }
    float4* op = (float4*)(out + (size_t)i * 16);
    op[0] = make_float4(acc[0], acc[1], acc[2], acc[3]);
    op[1] = make_float4(acc[4], acc[5], acc[6], acc[7]);
    op[2] = make_float4(acc[8], acc[9], acc[10], acc[11]);
    op[3] = make_float4(acc[12], acc[13], acc[14], acc[15]);
}

// Load one 16-float feature row via 4x float4 into an explicit array (no UB).
__device__ __forceinline__ void load_row(const float* __restrict__ h, int s,
                                         float v[16]) {
    const float4* hr = (const float4*)(h + (size_t)s * 16);
    *(float4*)&v[0]  = hr[0];
    *(float4*)&v[4]  = hr[1];
    *(float4*)&v[8]  = hr[2];
    *(float4*)&v[12] = hr[3];
}

// Batched (4-deep) neighbor aggregation: issue all gathers, then FMA.
__device__ __forceinline__ void aggregate(const float* __restrict__ h,
                                          const int* __restrict__ csr,
                                          int base, int cnt,
                                          const float* __restrict__ dinv,
                                          float acc[16]) {
#pragma unroll
    for (int c = 0; c < 16; c++) acc[c] = 0.f;
    int j = 0;
    for (; j + 4 <= cnt; j += 4) {
        int s0 = csr[base + j];
        int s1 = csr[base + j + 1];
        int s2 = csr[base + j + 2];
        int s3 = csr[base + j + 3];
        float w0 = dinv[s0], w1 = dinv[s1], w2 = dinv[s2], w3 = dinv[s3];
        float fa[16], fb[16], fc[16], fd[16];
        load_row(h, s0, fa);
        load_row(h, s1, fb);
        load_row(h, s2, fc);
        load_row(h, s3, fd);
#pragma unroll
        for (int c = 0; c < 16; c++) {
            float v = fmaf(w0, fa[c], acc[c]);
            v = fmaf(w1, fb[c], v);
            v = fmaf(w2, fc[c], v);
            acc[c] = fmaf(w3, fd[c], v);
        }
    }
    for (; j < cnt; j++) {
        int s = csr[base + j];
        float w = dinv[s];
        float fv[16];
        load_row(h, s, fv);
#pragma unroll
        for (int c = 0; c < 16; c++) acc[c] = fmaf(w, fv[c], acc[c]);
    }
}

// Layer1 agg fused with gemm2: out = relu(agg(h) + b1) @ W2
__global__ __launch_bounds__(256) void aggA_k(const float* __restrict__ h,
                                              const int* __restrict__ csr,
                                              const int* __restrict__ rs,
                                              const int* __restrict__ deg,
                                              const float* __restrict__ dinv,
                                              const float* __restrict__ bias,
                                              const float* __restrict__ W2,
                                              float* __restrict__ out) {
    __shared__ float w[256];
    __shared__ float bb[16];
    w[threadIdx.x] = W2[threadIdx.x];
    if (threadIdx.x < 16) bb[threadIdx.x] = bias[threadIdx.x];
    __syncthreads();
    int i = blockIdx.x * 256 + threadIdx.x;
    if (i >= NNODES) return;
    float acc[16];
    aggregate(h, csr, rs[i], deg[i], dinv, acc);
    float di = dinv[i];
    float d2 = di * di;
    float fv[16];
    load_row(h, i, fv);
    float a[16];
#pragma unroll
    for (int c = 0; c < 16; c++)
        a[c] = fmaxf(fmaf(di, acc[c], fmaf(d2, fv[c], bb[c])), 0.f);
    float o[16];
#pragma unroll
    for (int c = 0; c < 16; c++) o[c] = 0.f;
#pragma unroll
    for (int k = 0; k < 16; k++) {
        float ak = a[k];
#pragma unroll
        for (int c = 0; c < 16; c++) o[c] = fmaf(ak, w[k * 16 + c], o[c]);
    }
    float4* op = (float4*)(out + (size_t)i * 16);
    op[0] = *(float4*)&o[0];
    op[1] = *(float4*)&o[4];
    op[2] = *(float4*)&o[8];
    op[3] = *(float4*)&o[12];
}

// Layer2 agg fused with the MLP head:
// a = relu(agg(h) + b2); t = relu(a@l1w + l1b); out = t@l2w + l2b
__global__ __launch_bounds__(256) void aggB_k(const float* __restrict__ h,
                                              const int* __restrict__ csr,
                                              const int* __restrict__ rs,
                                              const int* __restrict__ deg,
                                              const float* __restrict__ dinv,
                                              const float* __restrict__ bias,
                                              const float* __restrict__ l1w,
                                              const float* __restrict__ l1b,
                                              const float* __restrict__ l2w,
                                              const float* __restrict__ l2b,
                                              float* __restrict__ out) {
    __shared__ float w1[256];
    __shared__ float bb[16];
    __shared__ float bb1[16];
    __shared__ float w2[16];
    __shared__ float bb2;
    int t = threadIdx.x;
    w1[t] = l1w[t];
    if (t < 16) bb[t] = bias[t];
    if (t >= 16 && t < 32) bb1[t - 16] = l1b[t - 16];
    if (t >= 32 && t < 48) w2[t - 32] = l2w[t - 32];
    if (t == 48) bb2 = l2b[0];
    __syncthreads();
    int i = blockIdx.x * 256 + t;
    if (i >= NNODES) return;
    float acc[16];
    aggregate(h, csr, rs[i], deg[i], dinv, acc);
    float di = dinv[i];
    float d2 = di * di;
    float fv[16];
    load_row(h, i, fv);
    float a[16];
#pragma unroll
    for (int c = 0; c < 16; c++)
        a[c] = fmaxf(fmaf(di, acc[c], fmaf(d2, fv[c], bb[c])), 0.f);
    float o = bb2;
#pragma unroll
    for (int j = 0; j < 16; j++) {
        float s = bb1[j];
#pragma unroll
        for (int k = 0; k < 16; k++) s = fmaf(a[k], w1[k * 16 + j], s);
        o = fmaf(fmaxf(s, 0.f), w2[j], o);
    }
    out[i] = o;
}

extern "C" void kernel_launch(void* const* d_in, const int* in_sizes, int n_in,
                              void* d_out, int out_size, void* d_ws, size_t ws_size,
                              hipStream_t stream) {
    const float* x   = (const float*)d_in[0];
    const int*   ei  = (const int*)d_in[1];
    const float* W1  = (const float*)d_in[2];
    const float* b1  = (const float*)d_in[3];
    const float* W2  = (const float*)d_in[4];
    const float* b2  = (const float*)d_in[5];
    const float* l1w = (const float*)d_in[6];
    const float* l1b = (const float*)d_in[7];
    const float* l2w = (const float*)d_in[8];
    const float* l2b = (const float*)d_in[9];
    float* out = (float*)d_out;

    char* ws = (char*)d_ws;
    size_t off = 0;
    auto alloc = [&](size_t bytes) {
        size_t o = off;
        off += (bytes + 255) & ~(size_t)255;
        return o;
    };
    int*   deg  = (int*)(ws + alloc((size_t)NNODES * 4));
    int*   rs   = (int*)(ws + alloc((size_t)NNODES * 4));
    int*   cur  = (int*)(ws + alloc((size_t)NNODES * 4));
    int*   bsum = (int*)(ws + alloc(512 * 4));
    float* dinv = (float*)(ws + alloc((size_t)NNODES * 4));
    int*   csr  = (int*)(ws + alloc((size_t)NEDGES * 4));
    float* buf0 = (float*)(ws + alloc((size_t)NNODES * 16 * 4));
    float* buf1 = (float*)(ws + alloc((size_t)NNODES * 16 * 4));

    const int* srcv = ei;
    const int* dstv = ei + NEDGES;

    const int NB_N = (NNODES + 255) / 256;  // 391
    const int NB_E = (NEDGES + 255) / 256;  // 12500

    hipMemsetAsync(deg, 0, (size_t)NNODES * 4, stream);
    hist_k<<<NB_E, 256, 0, stream>>>(dstv, deg);
    dinv_k<<<NB_N, 256, 0, stream>>>(deg, dinv);
    scan1_k<<<NB_N, 256, 0, stream>>>(deg, rs, bsum);
    scan2_k<<<1, 512, 0, stream>>>(bsum, NB_N);
    scan3_k<<<NB_N, 256, 0, stream>>>(rs, cur, bsum);
    fillp_k<<<250 * NRANGE, 256, 0, stream>>>(srcv, dstv, cur, csr);
    gemm1_k<<<NB_N, 256, 0, stream>>>(x, W1, buf0);
    aggA_k<<<NB_N, 256, 0, stream>>>(buf0, csr, rs, deg, dinv, b1, W2, buf1);
    aggB_k<<<NB_N, 256, 0, stream>>>(buf1, csr, rs, deg, dinv, b2,
                                     l1w, l1b, l2w, l2b, out);
}